// Round 9
// baseline (243.744 us; speedup 1.0000x reference)
//
#include <hip/hip_runtime.h>
#include <hip/hip_bf16.h>

typedef __bf16 bf16x8 __attribute__((ext_vector_type(8)));
typedef float f32x4 __attribute__((ext_vector_type(4)));
typedef unsigned short u16;

__device__ __forceinline__ u16 f2bf(float f) {
    union { float f; unsigned u; } x{f};
    unsigned r = x.u + 0x7fffu + ((x.u >> 16) & 1u);
    return (u16)(r >> 16);
}
// fast round-half-up pack of two fp32 -> packed bf16x2 (P >= 0, never NaN/Inf)
__device__ __forceinline__ unsigned pk2(float a, float b) {
    union { float f; unsigned u; } x{a}, y{b};
    return ((x.u + 0x8000u) >> 16) | ((y.u + 0x8000u) & 0xffff0000u);
}
// hardware exp2 (v_exp_f32); avoids glibc __exp2f macro collision
__device__ __forceinline__ float ex2(float x) { return __builtin_amdgcn_exp2f(x); }
__device__ __forceinline__ f32x4 zero4() { f32x4 z = {0.f, 0.f, 0.f, 0.f}; return z; }

// ======== prep: fused cast(hs->bf16) + W transposes + rope cos/sin tables ========
// blocks [0,4096): cast; [4096,7168): Wqkv^T; [7168,8192): Wo^T; [8192,8448): tables
__global__ void __launch_bounds__(256) prep(const float* __restrict__ hs,
                                            u16* __restrict__ Xb,
                                            const float* __restrict__ Wqkv,
                                            u16* __restrict__ Wqkvt,
                                            const float* __restrict__ Wo,
                                            u16* __restrict__ Wot,
                                            float* __restrict__ cosT,
                                            float* __restrict__ sinT) {
    __shared__ float tile[32][33];
    const int blk = blockIdx.x, t = threadIdx.x;
    if (blk < 4096) {                       // cast 4096*1024 fp32 -> bf16
        int i = (blk * 256 + t) * 4;
        float4 v = *(const float4*)(hs + i);
        ushort4 o;
        o.x = f2bf(v.x); o.y = f2bf(v.y); o.z = f2bf(v.z); o.w = f2bf(v.w);
        *(ushort4*)(Xb + i) = o;
    } else if (blk < 8192) {                // transpose+cast W[K][N] -> Wt[N][K]
        const float* W; u16* Wt; int N, bx, by;
        if (blk < 7168) { int bid = blk - 4096; W = Wqkv; Wt = Wqkvt; N = 3072; bx = bid % 96; by = bid / 96; }
        else            { int bid = blk - 7168; W = Wo;   Wt = Wot;   N = 1024; bx = bid % 32; by = bid / 32; }
        const int K = 1024;
        int tx = t & 31, ty = t >> 5;
        int n0 = bx * 32, k0 = by * 32;
#pragma unroll
        for (int i = 0; i < 32; i += 8)
            tile[ty + i][tx] = W[(size_t)(k0 + ty + i) * N + n0 + tx];
        __syncthreads();
#pragma unroll
        for (int i = 0; i < 32; i += 8)
            Wt[(size_t)(n0 + ty + i) * K + k0 + tx] = f2bf(tile[tx][ty + i]);
    } else {                                // rope tables: [2048][32] fp32
        int idx = (blk - 8192) * 256 + t;   // 65536
        int d = idx & 31, s = idx >> 5;
        float inv = expf(-(float)d * 0.374466538f);   // ln(160000)/32
        float th = (float)s * inv;
        cosT[idx] = cosf(th);
        sinT[idx] = sinf(th);
    }
}

// ======== pipelined GEMM K-loop, A direct-to-register (B via LDS) ========
// 128x128 tile, BK=32, 4 waves (2x2), wave = 64x64 (4x4 frags of 16x16x32).
// A-frag rows are wave-private: lane (m16,q4) loads its 16B frag straight from
// global (wave touches 16 rows x 64B = same line count as a coalesced 1KB load,
// L2-resident), prefetched one iter ahead. Only B stages through LDS:
// LDS ops/iter/wave drop 12 -> 6 (the R8 post-mortem bottleneck).
struct GemmCtx {
    f32x4 acc[4][4];
    int m16, q4, wm, wn;
};
template <int KDIM>
__device__ __forceinline__ void gemm_loop(const u16* __restrict__ A,
                                          const u16* __restrict__ Bt,
                                          int bm, int bn, GemmCtx& cx,
                                          u16 (*Bs)[128][40]) {
    const int t = threadIdx.x;
    const int lane = t & 63, w = t >> 6;
    cx.wm = w >> 1; cx.wn = w & 1;
    cx.m16 = lane & 15; cx.q4 = lane >> 4;
    const int r = t >> 1, c0 = (t & 1) * 16;

    const u16* Bg = Bt + (size_t)(bn * 128 + r) * KDIM + c0;
    const u16* Ag = A + (size_t)(bm * 128 + cx.wm * 64 + cx.m16) * KDIM + cx.q4 * 8;

#pragma unroll
    for (int i = 0; i < 4; i++)
#pragma unroll
        for (int j = 0; j < 4; j++) cx.acc[i][j] = zero4();

    // prefetch iter 0
    uint4 b0 = *(const uint4*)(Bg);
    uint4 b1 = *(const uint4*)(Bg + 8);
    bf16x8 afn[4];
#pragma unroll
    for (int i = 0; i < 4; i++)
        afn[i] = *(const bf16x8*)(Ag + (size_t)i * 16 * KDIM);

#pragma unroll
    for (int k0 = 0; k0 < KDIM; k0 += 32) {
        const int bi = (k0 >> 5) & 1;
        *(uint4*)&Bs[bi][r][c0] = b0;
        *(uint4*)&Bs[bi][r][c0 + 8] = b1;
        bf16x8 af[4];
#pragma unroll
        for (int i = 0; i < 4; i++) af[i] = afn[i];
        if (k0 + 32 < KDIM) {
            b0 = *(const uint4*)(Bg + k0 + 32);
            b1 = *(const uint4*)(Bg + k0 + 40);
#pragma unroll
            for (int i = 0; i < 4; i++)
                afn[i] = *(const bf16x8*)(Ag + k0 + 32 + (size_t)i * 16 * KDIM);
        }
        __syncthreads();                 // single barrier per iteration
        bf16x8 bf[4];
#pragma unroll
        for (int j = 0; j < 4; j++)
            bf[j] = *(const bf16x8*)&Bs[bi][cx.wn * 64 + j * 16 + cx.m16][cx.q4 * 8];
#pragma unroll
        for (int i = 0; i < 4; i++)
#pragma unroll
            for (int j = 0; j < 4; j++)
                cx.acc[i][j] = __builtin_amdgcn_mfma_f32_16x16x32_bf16(af[i], bf[j], cx.acc[i][j], 0, 0, 0);
    }
}

// ======== gemm_qkv: X @ Wqkv^T -> rope'd Q,K [bh][s][d] + V transposed [bh][d][s] ====
__global__ void __launch_bounds__(256) gemm_qkv(const u16* __restrict__ A,
                                                const u16* __restrict__ Bt,
                                                const float* __restrict__ cosT,
                                                const float* __restrict__ sinT,
                                                u16* __restrict__ Q,
                                                u16* __restrict__ Kd,
                                                u16* __restrict__ Vt) {
    __shared__ __align__(16) u16 Bs[2][128][40];
    GemmCtx cx;
    const int bm = blockIdx.y, bn = blockIdx.x;
    gemm_loop<1024>(A, Bt, bm, bn, cx, Bs);
    const int m16 = cx.m16, q4 = cx.q4;

    // epilogue: wave covers 64 cols = one (type, head); rows = tokens
    const int colbase = bn * 128 + cx.wn * 64;
    const int type = colbase >> 10;            // 0=Q 1=K 2=V
    const int h = (colbase & 1023) >> 6;
    const int rbase = bm * 128 + cx.wm * 64;

    if (type == 2) {
        // V transposed: Vt[bh][d][s]; lane's rr=0..3 are 4 consecutive s -> 8B store
#pragma unroll
        for (int i = 0; i < 4; i++) {
            int s0 = rbase + i * 16 + q4 * 4;
            int b = s0 >> 11, sl = s0 & 2047;
            size_t ob = (size_t)(b * 16 + h) * 64 * 2048;
#pragma unroll
            for (int j = 0; j < 4; j++) {
                int d = j * 16 + m16;
                ushort4 o;
                o.x = f2bf(cx.acc[i][j][0]);
                o.y = f2bf(cx.acc[i][j][1]);
                o.z = f2bf(cx.acc[i][j][2]);
                o.w = f2bf(cx.acc[i][j][3]);
                *(ushort4*)&Vt[ob + (size_t)d * 2048 + sl] = o;
            }
        }
    } else {
        u16* dst = (type == 0) ? Q : Kd;
        const float qs = (type == 0) ? 0.1803368801f /*0.125*log2(e)*/ : 1.0f;
#pragma unroll
        for (int i = 0; i < 4; i++)
#pragma unroll
            for (int rr = 0; rr < 4; rr++) {
                int r = rbase + i * 16 + q4 * 4 + rr;
                int b = r >> 11, s = r & 2047;
                size_t ob = ((size_t)((b * 16 + h) * 2048 + s)) * 64;
#pragma unroll
                for (int j2 = 0; j2 < 2; j2++) {
                    int d = j2 * 16 + m16;                 // d in [0,32)
                    float cs = cosT[s * 32 + d];
                    float sn = sinT[s * 32 + d];
                    float x1 = cx.acc[i][j2][rr];
                    float x2 = cx.acc[i][j2 + 2][rr];
                    dst[ob + d]      = f2bf((x1 * cs - x2 * sn) * qs);
                    dst[ob + d + 32] = f2bf((x2 * cs + x1 * sn) * qs);
                }
            }
    }
}

// ---------------- out-proj GEMM: C[M,N] fp32 = A[M,K] @ Bt[N,K]^T ----------------
__global__ void __launch_bounds__(256) gemm_out(const u16* __restrict__ A,
                                                const u16* __restrict__ Bt,
                                                float* __restrict__ C) {
    __shared__ __align__(16) u16 Bs[2][128][40];
    GemmCtx cx;
    const int bm = blockIdx.y, bn = blockIdx.x;
    gemm_loop<1024>(A, Bt, bm, bn, cx, Bs);
    const int N = 1024;
#pragma unroll
    for (int i = 0; i < 4; i++)
#pragma unroll
        for (int j = 0; j < 4; j++)
#pragma unroll
            for (int rr = 0; rr < 4; rr++) {
                int row = bm * 128 + cx.wm * 64 + i * 16 + cx.q4 * 4 + rr;
                int col = bn * 128 + cx.wn * 64 + j * 16 + cx.m16;
                C[(size_t)row * N + col] = cx.acc[i][j][rr];
            }
}

// ---------------- causal flash attention: 128 q-rows/block, 2 q-groups/wave ----------------
// grid (16, B*nh): block bx owns q rows [128bx, 128bx+128); K-tiles jt=0..2bx+1.
// Wave w computes q-groups g0 = 128bx + w*16+m16 and g1 = g0+64 against each staged
// 64-key tile, REUSING kf/vf register frags across both groups: 32 MFMA per tile
// per wave vs 16, with K/V frag reads and staging unchanged (R8 bottleneck: LDS ops).
// S^T = mfma(K_frag, Q_frag); fixed exponent offset M=24; one barrier per tile.
__global__ void __launch_bounds__(256) attn_kernel(const u16* __restrict__ Q,
                                                   const u16* __restrict__ Kg_,
                                                   const u16* __restrict__ Vtg_,
                                                   u16* __restrict__ O) {
    __shared__ __align__(16) u16 Ks[2][64][72];     // [buf][key][d]
    __shared__ __align__(16) u16 Vt[2][64][72];     // [buf][d][key]
    __shared__ __align__(16) u16 Pt[4][2][16][72];  // [wave][grp][q][key]
    const int t = threadIdx.x, w = t >> 6;
    const int m16 = t & 15, q4 = (t & 63) >> 4;
    const int bx = blockIdx.x, bh = blockIdx.y;
    const size_t base = (size_t)bh * 2048 * 64;
    const int b = bh >> 4, h = bh & 15;
    const int skey = t >> 2, sc = (t & 3) * 16;

    const int jg0 = 2 * bx;          // g0's diagonal tile; g0 inactive past it
    const int jtmax = 2 * bx + 1;    // g1's diagonal tile (last tile)

    const int qrow0 = bx * 128 + w * 16 + m16;
    const u16* Qg = Q + base + (size_t)qrow0 * 64;
    bf16x8 qa0 = *(const bf16x8*)(Qg + q4 * 8);
    bf16x8 qa1 = *(const bf16x8*)(Qg + 32 + q4 * 8);
    bf16x8 qb0 = *(const bf16x8*)(Qg + 64 * 64 + q4 * 8);
    bf16x8 qb1 = *(const bf16x8*)(Qg + 64 * 64 + 32 + q4 * 8);

    f32x4 occ0[4], occ1[4];
#pragma unroll
    for (int dc = 0; dc < 4; dc++) { occ0[dc] = zero4(); occ1[dc] = zero4(); }
    float li0 = 0.f, li1 = 0.f;

    const u16* Kb0 = Kg_ + base + skey * 64 + sc;
    const u16* Vt0 = Vtg_ + base + (size_t)skey * 2048 + sc;
    uint4 ka = *(const uint4*)(Kb0);
    uint4 kb = *(const uint4*)(Kb0 + 8);
    uint4 va = *(const uint4*)(Vt0);
    uint4 vb = *(const uint4*)(Vt0 + 8);

#pragma unroll 1
    for (int jt = 0; jt <= jtmax; jt++) {
        const int bi = jt & 1;
        *(uint4*)&Ks[bi][skey][sc] = ka;
        *(uint4*)&Ks[bi][skey][sc + 8] = kb;
        *(uint4*)&Vt[bi][skey][sc] = va;
        *(uint4*)&Vt[bi][skey][sc + 8] = vb;
        if (jt < jtmax) {
            const u16* Kn = Kb0 + (size_t)(jt + 1) * 4096;
            const u16* Vn = Vt0 + (size_t)(jt + 1) * 64;
            ka = *(const uint4*)(Kn);
            kb = *(const uint4*)(Kn + 8);
            va = *(const uint4*)(Vn);
            vb = *(const uint4*)(Vn + 8);
        }
        __syncthreads();   // single barrier per tile

        const bool g0act = (jt <= jg0);   // wave-uniform

        // S^T for both groups, sharing kf frags
        f32x4 st0[4], st1[4];
#pragma unroll
        for (int c = 0; c < 4; c++) { st0[c] = zero4(); st1[c] = zero4(); }
#pragma unroll
        for (int c = 0; c < 4; c++) {
            bf16x8 kf0 = *(const bf16x8*)&Ks[bi][c * 16 + m16][q4 * 8];
            bf16x8 kf1 = *(const bf16x8*)&Ks[bi][c * 16 + m16][32 + q4 * 8];
            if (g0act) {
                st0[c] = __builtin_amdgcn_mfma_f32_16x16x32_bf16(kf0, qa0, st0[c], 0, 0, 0);
                st0[c] = __builtin_amdgcn_mfma_f32_16x16x32_bf16(kf1, qa1, st0[c], 0, 0, 0);
            }
            st1[c] = __builtin_amdgcn_mfma_f32_16x16x32_bf16(kf0, qb0, st1[c], 0, 0, 0);
            st1[c] = __builtin_amdgcn_mfma_f32_16x16x32_bf16(kf1, qb1, st1[c], 0, 0, 0);
        }

        // softmax g0
        if (g0act) {
            float pv[4][4];
#pragma unroll
            for (int c = 0; c < 4; c++)
#pragma unroll
                for (int rr = 0; rr < 4; rr++) pv[c][rr] = st0[c][rr];
            if (jt == jg0) {
                const int ql = w * 16 + m16;
#pragma unroll
                for (int c = 0; c < 4; c++)
#pragma unroll
                    for (int rr = 0; rr < 4; rr++)
                        if (c * 16 + q4 * 4 + rr > ql) pv[c][rr] = -1e30f;
            }
#pragma unroll
            for (int c = 0; c < 4; c++) {
                float p0 = ex2(pv[c][0] - 24.f);
                float p1 = ex2(pv[c][1] - 24.f);
                float p2 = ex2(pv[c][2] - 24.f);
                float p3 = ex2(pv[c][3] - 24.f);
                li0 += (p0 + p1) + (p2 + p3);
                *(uint2*)&Pt[w][0][m16][c * 16 + q4 * 4] = make_uint2(pk2(p0, p1), pk2(p2, p3));
            }
        }
        // softmax g1
        {
            float pv[4][4];
#pragma unroll
            for (int c = 0; c < 4; c++)
#pragma unroll
                for (int rr = 0; rr < 4; rr++) pv[c][rr] = st1[c][rr];
            if (jt == jtmax) {
                const int ql = w * 16 + m16;
#pragma unroll
                for (int c = 0; c < 4; c++)
#pragma unroll
                    for (int rr = 0; rr < 4; rr++)
                        if (c * 16 + q4 * 4 + rr > ql) pv[c][rr] = -1e30f;
            }
#pragma unroll
            for (int c = 0; c < 4; c++) {
                float p0 = ex2(pv[c][0] - 24.f);
                float p1 = ex2(pv[c][1] - 24.f);
                float p2 = ex2(pv[c][2] - 24.f);
                float p3 = ex2(pv[c][3] - 24.f);
                li1 += (p0 + p1) + (p2 + p3);
                *(uint2*)&Pt[w][1][m16][c * 16 + q4 * 4] = make_uint2(pk2(p0, p1), pk2(p2, p3));
            }
        }

        // O^T += V^T @ P^T for both groups, sharing vf frags
#pragma unroll
        for (int ks = 0; ks < 2; ks++) {
            bf16x8 pf0, pf1;
            if (g0act) pf0 = *(const bf16x8*)&Pt[w][0][m16][ks * 32 + q4 * 8];
            pf1 = *(const bf16x8*)&Pt[w][1][m16][ks * 32 + q4 * 8];
#pragma unroll
            for (int dc = 0; dc < 4; dc++) {
                bf16x8 vf = *(const bf16x8*)&Vt[bi][dc * 16 + m16][ks * 32 + q4 * 8];
                if (g0act)
                    occ0[dc] = __builtin_amdgcn_mfma_f32_16x16x32_bf16(vf, pf0, occ0[dc], 0, 0, 0);
                occ1[dc] = __builtin_amdgcn_mfma_f32_16x16x32_bf16(vf, pf1, occ1[dc], 0, 0, 0);
            }
        }
    }

    // epilogue: both q-groups
    li0 += __shfl_xor(li0, 16); li0 += __shfl_xor(li0, 32);
    li1 += __shfl_xor(li1, 16); li1 += __shfl_xor(li1, 32);
    float r0 = 1.0f / li0, r1 = 1.0f / li1;
    u16* Op0 = O + ((size_t)(b * 2048 + qrow0)) * 1024 + h * 64 + q4 * 4;
    u16* Op1 = O + ((size_t)(b * 2048 + qrow0 + 64)) * 1024 + h * 64 + q4 * 4;
#pragma unroll
    for (int dc = 0; dc < 4; dc++) {
        ushort4 o;
        o.x = f2bf(occ0[dc][0] * r0);
        o.y = f2bf(occ0[dc][1] * r0);
        o.z = f2bf(occ0[dc][2] * r0);
        o.w = f2bf(occ0[dc][3] * r0);
        *(ushort4*)(Op0 + dc * 16) = o;
        ushort4 p;
        p.x = f2bf(occ1[dc][0] * r1);
        p.y = f2bf(occ1[dc][1] * r1);
        p.z = f2bf(occ1[dc][2] * r1);
        p.w = f2bf(occ1[dc][3] * r1);
        *(ushort4*)(Op1 + dc * 16) = p;
    }
}

extern "C" void kernel_launch(void* const* d_in, const int* in_sizes, int n_in,
                              void* d_out, int out_size, void* d_ws, size_t ws_size,
                              hipStream_t stream) {
    const float* hs   = (const float*)d_in[0];
    const float* Wqkv = (const float*)d_in[2];
    const float* Wo   = (const float*)d_in[3];
    float* out = (float*)d_out;

    const int BS = 4096;
    const int H = 1024, N3 = 3072;
    const int SH = 32 * 2048 * 64;

    u16* Xb    = (u16*)d_ws;                 // [4096,1024]
    u16* Wqkvt = Xb + (size_t)BS * H;        // [3072,1024]
    u16* Wot   = Wqkvt + (size_t)N3 * H;     // [1024,1024]
    u16* Qb    = Wot + (size_t)H * H;        // [bh][s][d]
    u16* Kb    = Qb + SH;
    u16* Vtb   = Kb + SH;                    // [bh][d][s] (written transposed)
    u16* AOb   = Vtb + SH;                   // [4096,1024] bf16
    float* cosT = (float*)(AOb + (size_t)BS * H);   // [2048][32]
    float* sinT = cosT + 2048 * 32;

    prep<<<8448, 256, 0, stream>>>(hs, Xb, Wqkv, Wqkvt, Wo, Wot, cosT, sinT);

    gemm_qkv<<<dim3(N3 / 128, BS / 128), 256, 0, stream>>>(Xb, Wqkvt, cosT, sinT,
                                                           Qb, Kb, Vtb);

    attn_kernel<<<dim3(16, 32), 256, 0, stream>>>(Qb, Kb, Vtb, AOb);

    gemm_out<<<dim3(H / 128, BS / 128), 256, 0, stream>>>(AOb, Wot, out);
}

// Round 10
// 199.970 us; speedup vs baseline: 1.2189x; 1.2189x over previous
//
#include <hip/hip_runtime.h>
#include <hip/hip_bf16.h>

typedef __bf16 bf16x8 __attribute__((ext_vector_type(8)));
typedef float f32x4 __attribute__((ext_vector_type(4)));
typedef unsigned short u16;

__device__ __forceinline__ u16 f2bf(float f) {
    union { float f; unsigned u; } x{f};
    unsigned r = x.u + 0x7fffu + ((x.u >> 16) & 1u);
    return (u16)(r >> 16);
}
// fast round-half-up pack of two fp32 -> packed bf16x2 (P >= 0, never NaN/Inf)
__device__ __forceinline__ unsigned pk2(float a, float b) {
    union { float f; unsigned u; } x{a}, y{b};
    return ((x.u + 0x8000u) >> 16) | ((y.u + 0x8000u) & 0xffff0000u);
}
// hardware exp2 (v_exp_f32); avoids glibc __exp2f macro collision
__device__ __forceinline__ float ex2(float x) { return __builtin_amdgcn_exp2f(x); }
__device__ __forceinline__ f32x4 zero4() { f32x4 z = {0.f, 0.f, 0.f, 0.f}; return z; }

// async global->LDS, 16B per lane; HW writes lane i at ldsbase + i*16
typedef const __attribute__((address_space(1))) unsigned int* gp1_t;
typedef __attribute__((address_space(3))) unsigned int* lp3_t;
__device__ __forceinline__ void async16(const u16* g, u16* l) {
    __builtin_amdgcn_global_load_lds((gp1_t)g, (lp3_t)l, 16, 0, 0);
}

// ======== prep: fused cast(hs->bf16) + W transposes + rope cos/sin tables ========
// blocks [0,4096): cast; [4096,7168): Wqkv^T; [7168,8192): Wo^T; [8192,8448): tables
__global__ void __launch_bounds__(256) prep(const float* __restrict__ hs,
                                            u16* __restrict__ Xb,
                                            const float* __restrict__ Wqkv,
                                            u16* __restrict__ Wqkvt,
                                            const float* __restrict__ Wo,
                                            u16* __restrict__ Wot,
                                            float* __restrict__ cosT,
                                            float* __restrict__ sinT) {
    __shared__ float tile[32][33];
    const int blk = blockIdx.x, t = threadIdx.x;
    if (blk < 4096) {                       // cast 4096*1024 fp32 -> bf16
        int i = (blk * 256 + t) * 4;
        float4 v = *(const float4*)(hs + i);
        ushort4 o;
        o.x = f2bf(v.x); o.y = f2bf(v.y); o.z = f2bf(v.z); o.w = f2bf(v.w);
        *(ushort4*)(Xb + i) = o;
    } else if (blk < 8192) {                // transpose+cast W[K][N] -> Wt[N][K]
        const float* W; u16* Wt; int N, bx, by;
        if (blk < 7168) { int bid = blk - 4096; W = Wqkv; Wt = Wqkvt; N = 3072; bx = bid % 96; by = bid / 96; }
        else            { int bid = blk - 7168; W = Wo;   Wt = Wot;   N = 1024; bx = bid % 32; by = bid / 32; }
        const int K = 1024;
        int tx = t & 31, ty = t >> 5;
        int n0 = bx * 32, k0 = by * 32;
#pragma unroll
        for (int i = 0; i < 32; i += 8)
            tile[ty + i][tx] = W[(size_t)(k0 + ty + i) * N + n0 + tx];
        __syncthreads();
#pragma unroll
        for (int i = 0; i < 32; i += 8)
            Wt[(size_t)(n0 + ty + i) * K + k0 + tx] = f2bf(tile[tx][ty + i]);
    } else {                                // rope tables: [2048][32] fp32
        int idx = (blk - 8192) * 256 + t;   // 65536
        int d = idx & 31, s = idx >> 5;
        float inv = expf(-(float)d * 0.374466538f);   // ln(160000)/32
        float th = (float)s * inv;
        cosT[idx] = cosf(th);
        sinT[idx] = sinf(th);
    }
}

// ======== GEMM K-loop (R7 measured-best): async global_load_lds + XOR swizzle ========
// 128x128 tile, BK=32, 256 thr = 4 waves (2x2), wave = 64x64 (4x4 frags).
// LDS unpadded [128][32]; global k-chunk gather XOR-swizzled so frag ds_read_b128
// is 2-way (free): LDS(row, unit) holds global chunk unit ^ ((row>>1)&3).
struct GemmCtx {
    f32x4 acc[4][4];
    int m16, q4, wm, wn;
};
template <int KDIM>
__device__ __forceinline__ void gemm_loop(const u16* __restrict__ A,
                                          const u16* __restrict__ Bt,
                                          int bm, int bn, GemmCtx& cx,
                                          u16* As, u16* Bs) {
    const int t = threadIdx.x;
    const int lane = t & 63, w = t >> 6;
    cx.wm = w >> 1; cx.wn = w & 1;
    cx.m16 = lane & 15; cx.q4 = lane >> 4;

    const int lrow = lane >> 2;
    const int kchunk = (lane & 3) ^ ((lane >> 3) & 3);   // swizzled global gather
    const u16* Ag = A + (size_t)(bm * 128 + w * 32 + lrow) * KDIM + kchunk * 8;
    const u16* Bg = Bt + (size_t)(bn * 128 + w * 32 + lrow) * KDIM + kchunk * 8;
    u16* Al0 = As + (w * 32) * 32;
    u16* Al1 = As + (w * 32 + 16) * 32;
    u16* Bl0 = Bs + (w * 32) * 32;
    u16* Bl1 = Bs + (w * 32 + 16) * 32;
    const int kswz = (cx.q4 ^ ((cx.m16 >> 1) & 3)) * 8;

#pragma unroll
    for (int i = 0; i < 4; i++)
#pragma unroll
        for (int j = 0; j < 4; j++) cx.acc[i][j] = zero4();

    for (int k0 = 0; k0 < KDIM; k0 += 32) {
        __syncthreads();                 // prior iter's frag reads complete
        async16(Ag + k0, Al0);
        async16(Ag + 16 * KDIM + k0, Al1);
        async16(Bg + k0, Bl0);
        async16(Bg + 16 * KDIM + k0, Bl1);
        __syncthreads();                 // drains vmcnt: LDS data visible
        bf16x8 af[4], bf[4];
#pragma unroll
        for (int i = 0; i < 4; i++)
            af[i] = *(const bf16x8*)&As[(cx.wm * 64 + i * 16 + cx.m16) * 32 + kswz];
#pragma unroll
        for (int j = 0; j < 4; j++)
            bf[j] = *(const bf16x8*)&Bs[(cx.wn * 64 + j * 16 + cx.m16) * 32 + kswz];
#pragma unroll
        for (int i = 0; i < 4; i++)
#pragma unroll
            for (int j = 0; j < 4; j++)
                cx.acc[i][j] = __builtin_amdgcn_mfma_f32_16x16x32_bf16(af[i], bf[j], cx.acc[i][j], 0, 0, 0);
    }
}

// ======== gemm_qkv: X @ Wqkv^T -> rope'd Q,K [bh][s][d] + V transposed [bh][d][s] ====
__global__ void __launch_bounds__(256) gemm_qkv(const u16* __restrict__ A,
                                                const u16* __restrict__ Bt,
                                                const float* __restrict__ cosT,
                                                const float* __restrict__ sinT,
                                                u16* __restrict__ Q,
                                                u16* __restrict__ Kd,
                                                u16* __restrict__ Vt) {
    __shared__ __align__(16) u16 As[128 * 32];
    __shared__ __align__(16) u16 Bs[128 * 32];
    GemmCtx cx;
    const int bm = blockIdx.y, bn = blockIdx.x;
    gemm_loop<1024>(A, Bt, bm, bn, cx, As, Bs);
    const int m16 = cx.m16, q4 = cx.q4;

    // epilogue: wave covers 64 cols = one (type, head); rows = tokens
    const int colbase = bn * 128 + cx.wn * 64;
    const int type = colbase >> 10;            // 0=Q 1=K 2=V
    const int h = (colbase & 1023) >> 6;
    const int rbase = bm * 128 + cx.wm * 64;

    if (type == 2) {
        // V transposed: Vt[bh][d][s]; lane's rr=0..3 are 4 consecutive s -> 8B store
#pragma unroll
        for (int i = 0; i < 4; i++) {
            int s0 = rbase + i * 16 + q4 * 4;
            int b = s0 >> 11, sl = s0 & 2047;
            size_t ob = (size_t)(b * 16 + h) * 64 * 2048;
#pragma unroll
            for (int j = 0; j < 4; j++) {
                int d = j * 16 + m16;
                ushort4 o;
                o.x = f2bf(cx.acc[i][j][0]);
                o.y = f2bf(cx.acc[i][j][1]);
                o.z = f2bf(cx.acc[i][j][2]);
                o.w = f2bf(cx.acc[i][j][3]);
                *(ushort4*)&Vt[ob + (size_t)d * 2048 + sl] = o;
            }
        }
    } else {
        u16* dst = (type == 0) ? Q : Kd;
        const float qs = (type == 0) ? 0.1803368801f /*0.125*log2(e)*/ : 1.0f;
#pragma unroll
        for (int i = 0; i < 4; i++)
#pragma unroll
            for (int rr = 0; rr < 4; rr++) {
                int r = rbase + i * 16 + q4 * 4 + rr;
                int b = r >> 11, s = r & 2047;
                size_t ob = ((size_t)((b * 16 + h) * 2048 + s)) * 64;
#pragma unroll
                for (int j2 = 0; j2 < 2; j2++) {
                    int d = j2 * 16 + m16;                 // d in [0,32)
                    float cs = cosT[s * 32 + d];
                    float sn = sinT[s * 32 + d];
                    float x1 = cx.acc[i][j2][rr];
                    float x2 = cx.acc[i][j2 + 2][rr];
                    dst[ob + d]      = f2bf((x1 * cs - x2 * sn) * qs);
                    dst[ob + d + 32] = f2bf((x2 * cs + x1 * sn) * qs);
                }
            }
    }
}

// ---------------- out-proj GEMM: C[M,N] fp32 = A[M,K] @ Bt[N,K]^T ----------------
__global__ void __launch_bounds__(256) gemm_out(const u16* __restrict__ A,
                                                const u16* __restrict__ Bt,
                                                float* __restrict__ C) {
    __shared__ __align__(16) u16 As[128 * 32];
    __shared__ __align__(16) u16 Bs[128 * 32];
    GemmCtx cx;
    const int bm = blockIdx.y, bn = blockIdx.x;
    gemm_loop<1024>(A, Bt, bm, bn, cx, As, Bs);
    const int N = 1024;
#pragma unroll
    for (int i = 0; i < 4; i++)
#pragma unroll
        for (int j = 0; j < 4; j++)
#pragma unroll
            for (int rr = 0; rr < 4; rr++) {
                int row = bm * 128 + cx.wm * 64 + i * 16 + cx.q4 * 4 + rr;
                int col = bn * 128 + cx.wn * 64 + j * 16 + cx.m16;
                C[(size_t)row * N + col] = cx.acc[i][j][rr];
            }
}

// ---------------- causal flash attention: 512 thr, 8 waves, 128 q-rows/phase ----------------
// grid (8, B*nh): block bx handles supertile pair {bx, 15-bx} -> exactly 34 K-tiles
// per block (R8's perfect balance + R9's halved staging/fetch). Each wave owns one
// 16-q-row group; per-thread staging is 16B K + 16B V per tile. Waves whose diagonal
// tile jd = 2*st + (w>=4) has passed skip compute but keep barriers.
// S^T = mfma(K_frag, Q_frag); fixed exponent offset M=24; one barrier per tile.
__global__ void __launch_bounds__(512) attn_kernel(const u16* __restrict__ Q,
                                                   const u16* __restrict__ Kg_,
                                                   const u16* __restrict__ Vtg_,
                                                   u16* __restrict__ O) {
    __shared__ __align__(16) u16 Ks[2][64][72];     // [buf][key][d]
    __shared__ __align__(16) u16 Vs[2][64][72];     // [buf][d][key]
    __shared__ __align__(16) u16 Pt[8][16][72];     // [wave][q][key]
    const int t = threadIdx.x, w = t >> 6;
    const int m16 = t & 15, q4 = (t & 63) >> 4;
    const int bx = blockIdx.x, bh = blockIdx.y;
    const size_t base = (size_t)bh * 2048 * 64;
    const int b = bh >> 4, h = bh & 15;
    const int skey = t >> 3, sc = (t & 7) * 8;      // 16B staging per thread

#pragma unroll 1
    for (int ph = 0; ph < 2; ph++) {
        const int st = ph ? (15 - bx) : bx;
        const int qrow = st * 128 + w * 16 + m16;
        const u16* Qg = Q + base + (size_t)qrow * 64;
        bf16x8 qf0 = *(const bf16x8*)(Qg + q4 * 8);
        bf16x8 qf1 = *(const bf16x8*)(Qg + 32 + q4 * 8);

        f32x4 occ[4];
#pragma unroll
        for (int dc = 0; dc < 4; dc++) occ[dc] = zero4();
        float li = 0.f;

        const int jtmax = 2 * st + 1;
        const int jd = 2 * st + (w >> 2);   // this wave's diagonal tile

        const u16* Kb0 = Kg_ + base + skey * 64 + sc;            // + jt*4096
        const u16* Vt0 = Vtg_ + base + (size_t)skey * 2048 + sc; // + jt*64
        uint4 ka = *(const uint4*)(Kb0);
        uint4 va = *(const uint4*)(Vt0);

#pragma unroll 1
        for (int jt = 0; jt <= jtmax; jt++) {
            const int bi = jt & 1;
            *(uint4*)&Ks[bi][skey][sc] = ka;
            *(uint4*)&Vs[bi][skey][sc] = va;
            if (jt < jtmax) {
                ka = *(const uint4*)(Kb0 + (size_t)(jt + 1) * 4096);
                va = *(const uint4*)(Vt0 + (size_t)(jt + 1) * 64);
            }
            __syncthreads();   // single barrier per tile

            if (jt <= jd) {    // wave-uniform activity
                // S^T = K @ Q^T : col(m16)=q, key = c*16 + q4*4 + rr (log2 domain)
                f32x4 stv[4];
#pragma unroll
                for (int c = 0; c < 4; c++) stv[c] = zero4();
#pragma unroll
                for (int c = 0; c < 4; c++) {
                    bf16x8 kf0 = *(const bf16x8*)&Ks[bi][c * 16 + m16][q4 * 8];
                    bf16x8 kf1 = *(const bf16x8*)&Ks[bi][c * 16 + m16][32 + q4 * 8];
                    stv[c] = __builtin_amdgcn_mfma_f32_16x16x32_bf16(kf0, qf0, stv[c], 0, 0, 0);
                    stv[c] = __builtin_amdgcn_mfma_f32_16x16x32_bf16(kf1, qf1, stv[c], 0, 0, 0);
                }

                float pv[4][4];
#pragma unroll
                for (int c = 0; c < 4; c++)
#pragma unroll
                    for (int rr = 0; rr < 4; rr++) pv[c][rr] = stv[c][rr];
                if (jt == jd) {   // diagonal: mask key > q (lane-local q)
                    const int ql = qrow - 64 * jt;
#pragma unroll
                    for (int c = 0; c < 4; c++)
#pragma unroll
                        for (int rr = 0; rr < 4; rr++)
                            if (c * 16 + q4 * 4 + rr > ql) pv[c][rr] = -1e30f;
                }

                // fixed-max softmax: p = 2^(s' - 24)
#pragma unroll
                for (int c = 0; c < 4; c++) {
                    float p0 = ex2(pv[c][0] - 24.f);
                    float p1 = ex2(pv[c][1] - 24.f);
                    float p2 = ex2(pv[c][2] - 24.f);
                    float p3 = ex2(pv[c][3] - 24.f);
                    li += (p0 + p1) + (p2 + p3);
                    *(uint2*)&Pt[w][m16][c * 16 + q4 * 4] = make_uint2(pk2(p0, p1), pk2(p2, p3));
                }

                // O^T += V^T @ P^T
#pragma unroll
                for (int ks = 0; ks < 2; ks++) {
                    bf16x8 pf = *(const bf16x8*)&Pt[w][m16][ks * 32 + q4 * 8];
#pragma unroll
                    for (int dc = 0; dc < 4; dc++) {
                        bf16x8 vf = *(const bf16x8*)&Vs[bi][dc * 16 + m16][ks * 32 + q4 * 8];
                        occ[dc] = __builtin_amdgcn_mfma_f32_16x16x32_bf16(vf, pf, occ[dc], 0, 0, 0);
                    }
                }
            }
        }

        // epilogue: lane owns q-row qrow; d = dc*16 + q4*4 + rr
        li += __shfl_xor(li, 16);
        li += __shfl_xor(li, 32);
        float rli = 1.0f / li;
        u16* Op = O + ((size_t)(b * 2048 + qrow)) * 1024 + h * 64 + q4 * 4;
#pragma unroll
        for (int dc = 0; dc < 4; dc++) {
            ushort4 o;
            o.x = f2bf(occ[dc][0] * rli);
            o.y = f2bf(occ[dc][1] * rli);
            o.z = f2bf(occ[dc][2] * rli);
            o.w = f2bf(occ[dc][3] * rli);
            *(ushort4*)(Op + dc * 16) = o;
        }
        __syncthreads();  // protect LDS buffers across the phase boundary
    }
}

extern "C" void kernel_launch(void* const* d_in, const int* in_sizes, int n_in,
                              void* d_out, int out_size, void* d_ws, size_t ws_size,
                              hipStream_t stream) {
    const float* hs   = (const float*)d_in[0];
    const float* Wqkv = (const float*)d_in[2];
    const float* Wo   = (const float*)d_in[3];
    float* out = (float*)d_out;

    const int BS = 4096;
    const int H = 1024, N3 = 3072;
    const int SH = 32 * 2048 * 64;

    u16* Xb    = (u16*)d_ws;                 // [4096,1024]
    u16* Wqkvt = Xb + (size_t)BS * H;        // [3072,1024]
    u16* Wot   = Wqkvt + (size_t)N3 * H;     // [1024,1024]
    u16* Qb    = Wot + (size_t)H * H;        // [bh][s][d]
    u16* Kb    = Qb + SH;
    u16* Vtb   = Kb + SH;                    // [bh][d][s] (written transposed)
    u16* AOb   = Vtb + SH;                   // [4096,1024] bf16
    float* cosT = (float*)(AOb + (size_t)BS * H);   // [2048][32]
    float* sinT = cosT + 2048 * 32;

    prep<<<8448, 256, 0, stream>>>(hs, Xb, Wqkv, Wqkvt, Wo, Wot, cosT, sinT);

    gemm_qkv<<<dim3(N3 / 128, BS / 128), 256, 0, stream>>>(Xb, Wqkvt, cosT, sinT,
                                                           Qb, Kb, Vtb);

    attn_kernel<<<dim3(8, 32), 512, 0, stream>>>(Qb, Kb, Vtb, AOb);

    gemm_out<<<dim3(H / 128, BS / 128), 256, 0, stream>>>(AOb, Wot, out);
}